// Round 18
// baseline (64.886 us; speedup 1.0000x reference)
//
#include <hip/hip_runtime.h>

#define SCALE2  0.180336880f     // 0.125 * log2(e)  -> scores in log2 units
#define LOG2E   1.44269504089f
#define LN2     0.69314718056f

typedef __attribute__((ext_vector_type(4))) float f32x4;
typedef __attribute__((ext_vector_type(8))) short s16x8;   // 8 bf16 (4 VGPRs)

#define MFMA16 __builtin_amdgcn_mfma_f32_16x16x32_bf16
#define RAW_BARRIER() asm volatile("s_barrier" ::: "memory")

__device__ __forceinline__ unsigned short f2bf(float f){
  union { float f; unsigned u; } v; v.f = f;
  unsigned r = v.u + 0x7FFFu + ((v.u >> 16) & 1u);   // RNE
  return (unsigned short)(r >> 16);
}
__device__ __forceinline__ unsigned pk2r(float a, float b){   // RNE pack, a in low short
  return (unsigned)f2bf(a) | ((unsigned)f2bf(b) << 16);
}
__device__ __forceinline__ float bf2f(unsigned short u){
  union { unsigned u; float f; } v; v.u = ((unsigned)u) << 16; return v.f;
}
// truncating bf16 pack of (a,b) -> one dword via v_perm (1 instr); a in low short
__device__ __forceinline__ unsigned pk2t(float a, float b){
  return __builtin_amdgcn_perm(__float_as_uint(b), __float_as_uint(a), 0x07060302u);
}
__device__ __forceinline__ void gl16(const void* g, void* l){
  __builtin_amdgcn_global_load_lds((const __attribute__((address_space(1))) unsigned int*)g,
                                   (__attribute__((address_space(3))) unsigned int*)l, 16, 0, 0);
}

// ------- fp32->bf16 for Wqkv, Wproj, relpos table only (x is consumed fp32 by gemm_qkv) -------
__global__ void cvt_all(const float* __restrict__ wq, const float* __restrict__ wp,
                        const float* __restrict__ table,
                        unsigned short* __restrict__ wqb, unsigned short* __restrict__ wpb,
                        unsigned short* __restrict__ tableb){
  int idx = blockIdx.x * blockDim.x + threadIdx.x;
  if (idx < 262144){
    const float4* s; ushort4* d; int j;
    if (idx < 196608){ s = (const float4*)wq; d = (ushort4*)wqb; j = idx; }
    else { s = (const float4*)wp; d = (ushort4*)wpb; j = idx - 196608; }
    float4 v = s[j];
    ushort4 o;
    o.x = f2bf(v.x); o.y = f2bf(v.y); o.z = f2bf(v.z); o.w = f2bf(v.w);
    d[j] = o;
  } else {
    int j = idx - 262144;            // 0..4095 ; table is [3969][8]
    float tv[8] = {0,0,0,0,0,0,0,0};
    if (j < 3969){
      const float4* t4 = (const float4*)table + (size_t)j * 2;
      float4 f0 = t4[0], f1 = t4[1];
      tv[0]=f0.x; tv[1]=f0.y; tv[2]=f0.z; tv[3]=f0.w;
      tv[4]=f1.x; tv[5]=f1.y; tv[6]=f1.z; tv[7]=f1.w;
    }
    #pragma unroll
    for (int h = 0; h < 8; h++)
      tableb[(h << 12) + j] = f2bf(tv[h] * LOG2E);
  }
}

// ---- GEMM1: qkv = x(fp32) @ Wqkv^T, 64x128 tile; A reg-staged+converted, B gl16-dbuf ----
__global__ __launch_bounds__(256) void gemm_qkv(
    const float* __restrict__ A,             // x [4096][512] fp32
    const unsigned short* __restrict__ Bt,   // wqkvb [1536][512]
    unsigned short* __restrict__ qb, unsigned short* __restrict__ kb,
    unsigned short* __restrict__ vt2)        // [bh][32cc][32j][2dl][32k]
{
  __shared__ __align__(16) unsigned short lA[64*32];      // single-buffered (written in stage phase)
  __shared__ __align__(16) unsigned short lB[2][128*32];
  __shared__ __align__(16) unsigned short lT[64*130];     // V-transpose tile (epilogue only)
  const int tid = threadIdx.x;
  const int lane = tid & 63;
  const int wid  = tid >> 6;
  const int i = lane & 15, g = lane >> 4;
  const int m0 = blockIdx.x * 64;
  const int n0 = blockIdx.y * 128;
  const int wr = wid >> 1, wc = wid & 1;   // wave tile 32 x 64
  const int K = 512;
  const int srA = tid >> 2;                // 0..63
  const int scc = (tid & 3) * 8;
  const float* ApF = A + (size_t)(m0 + srA) * K + scc;
  const unsigned short* BpS0 = Bt + (size_t)(n0 + srA) * K + scc;
  const unsigned short* BpS1 = Bt + (size_t)(n0 + 64 + srA) * K + scc;
  unsigned short* lAd = &lA[srA*32 + scc];

  auto STAGEB = [&](int buf, int k0){
    gl16(BpS0 + k0, &lB[buf][srA*32 + scc]);
    gl16(BpS1 + k0, &lB[buf][(64 + srA)*32 + scc]);
  };

  f32x4 acc[2][4] = {};
  float4 a0c, a1c, a0n, a1n;
  a0c = *(const float4*)(ApF);
  a1c = *(const float4*)(ApF + 4);
  STAGEB(0, 0);

  for (int k0 = 0; k0 < K; k0 += 32){
    const int buf = (k0 >> 5) & 1;
    RAW_BARRIER();                       // prev readers of lA / lB[buf^1] done
    // write A(k) (compiler waits its regs: vmcnt(2), leaves B(k) in flight)
    {
      uint4 aw;
      aw.x = pk2r(a0c.x, a0c.y);
      aw.y = pk2r(a0c.z, a0c.w);
      aw.z = pk2r(a1c.x, a1c.y);
      aw.w = pk2r(a1c.z, a1c.w);
      *(uint4*)lAd = aw;
    }
    if (k0 + 32 < K){
      a0n = *(const float4*)(ApF + k0 + 32);       // issue-early for next iter
      a1n = *(const float4*)(ApF + k0 + 36);
      STAGEB(buf ^ 1, k0 + 32);
      asm volatile("s_waitcnt lgkmcnt(0)" ::: "memory");   // A write visible
      asm volatile("s_waitcnt vmcnt(4)" ::: "memory");     // B(k) done; next streams in flight
    } else {
      asm volatile("s_waitcnt lgkmcnt(0)" ::: "memory");
      asm volatile("s_waitcnt vmcnt(0)" ::: "memory");
    }
    RAW_BARRIER();                       // all waves' stage_k visible
    s16x8 aF[2], bF[4];
    #pragma unroll
    for (int mi = 0; mi < 2; mi++)
      aF[mi] = *(const s16x8*)(&lA[(wr*32 + mi*16 + i)*32 + 8*g]);
    #pragma unroll
    for (int ni = 0; ni < 4; ni++)
      bF[ni] = *(const s16x8*)(&lB[buf][(wc*64 + ni*16 + i)*32 + 8*g]);
    #pragma unroll
    for (int mi = 0; mi < 2; mi++)
      #pragma unroll
      for (int ni = 0; ni < 4; ni++)
        acc[mi][ni] = MFMA16(aF[mi], bF[ni], acc[mi][ni], 0, 0, 0);
    a0c = a0n; a1c = a1n;
  }

  if (blockIdx.y < 8){
    // ---- q/k epilogue: [bh][tok][dh] scatter; q pre-scaled by SCALE2 ----
    #pragma unroll
    for (int mi = 0; mi < 2; mi++){
      #pragma unroll
      for (int r = 0; r < 4; r++){
        int row = m0 + wr*32 + mi*16 + 4*g + r;
        int b = row >> 10, tok = row & 1023;
        #pragma unroll
        for (int ni = 0; ni < 4; ni++){
          int col = n0 + wc*64 + ni*16 + i;
          int part = col >> 9;
          float av = acc[mi][ni][r];
          unsigned short bv = f2bf(part == 0 ? av * SCALE2 : av);
          int hh = (col >> 6) & 7;
          int dh = col & 63;
          int bh = b * 8 + hh;
          unsigned short* dst = (part == 0) ? qb : kb;
          dst[((size_t)(bh << 10) + tok) * 64 + dh] = bv;
        }
      }
    }
  } else {
    // ---- V epilogue: transpose in LDS, write vt2 coalesced ----
    #pragma unroll
    for (int mi = 0; mi < 2; mi++){
      #pragma unroll
      for (int r = 0; r < 4; r++){
        int lt = wr*32 + mi*16 + 4*g + r;          // local tok
        #pragma unroll
        for (int ni = 0; ni < 4; ni++){
          int lc = wc*64 + ni*16 + i;              // local col 0..127
          lT[lt*130 + lc] = f2bf(acc[mi][ni][r]);
        }
      }
    }
    __syncthreads();
    const int b    = m0 >> 10;
    const int tok0 = m0 & 1023;
    const int lc   = tid >> 1;                     // 0..127
    const int half = tid & 1;                      // which 32-tok chunk
    const int h    = (blockIdx.y - 8)*2 + (lc >> 6);
    const int dh   = lc & 63;
    const int bh   = b*8 + h;
    const int cc   = (tok0 >> 5) + half;
    union { s16x8 v[4]; unsigned short u[32]; } o;
    #pragma unroll
    for (int kk = 0; kk < 32; kk++)
      o.u[kk] = lT[(half*32 + kk)*130 + lc];
    unsigned short* dst = vt2 + (size_t)bh*65536 + ((size_t)cc*32 + (dh >> 1))*64 + (dh & 1)*32;
    *(s16x8*)(dst +  0) = o.v[0];
    *(s16x8*)(dst +  8) = o.v[1];
    *(s16x8*)(dst + 16) = o.v[2];
    *(s16x8*)(dst + 24) = o.v[3];
  }
}

// ---- Flash attention v13 (R17-best): bias as MFMA C-init + pre-scaled Q ----
#define SM_KOFF 0
#define SM_VOFF 16384
#define SM_SIZE 32768
__global__ __launch_bounds__(256, 4) void attn(
    const unsigned short* __restrict__ qb,     // pre-scaled by SCALE2
    const unsigned short* __restrict__ kb,
    const unsigned short* __restrict__ vt2,    // [bh][32cc][32j][2dl][32k]
    const unsigned short* __restrict__ tableb, // [8][4096] bf16, log2e-scaled
    unsigned short* __restrict__ yb,
    float* __restrict__ entp, float* __restrict__ maxp)
{
  __shared__ __align__(16) char smem[SM_SIZE];
  __shared__ float sE[2], sMx[2];

  const int tid = threadIdx.x, lane = tid & 63, w = tid >> 6;
  const int i = lane & 15, g = lane >> 4;

  // XCD-affine decode: all 32 blocks of one (b,h) share d&7 -> same XCD L2
  const int d  = blockIdx.x;
  const int bh = (d & 7) * 4 + (d >> 8);
  const int qt = (d >> 3) & 31;
  const int q0 = qt * 32;
  const int b  = bh >> 3;
  const int h  = bh & 7;

  const int qs = w & 1;        // q sub-tile
  const int s  = w >> 1;       // kv half

  const unsigned short* Qp = qb  + (size_t)bh * 65536;
  const unsigned short* Kp = kb  + (size_t)bh * 65536;
  const unsigned short* Vp = vt2 + (size_t)bh * 65536 + (size_t)s * 32768;
  const unsigned short* tb = tableb + (h << 12);

  const int n_ = q0 + qs*16 + i;
  s16x8 qf0 = *(const s16x8*)(Qp + (size_t)n_ * 64 + 8*g);
  s16x8 qf1 = *(const s16x8*)(Qp + (size_t)n_ * 64 + 32 + 8*g);

  const int slot = qs*64 + lane;
  const int rA0 = slot >> 3, rA1 = rA0 + 16;            // LDS dest rows
  const int cb0 = ((slot & 7)*16) ^ ((rA0 & 7) << 4);
  const int cb1 = ((slot & 7)*16) ^ ((rA1 & 7) << 4);
  // K storage permutation: LDS row x holds key 8*(x>>2)+(x&3) (+4 for x>=16)
  const int kA = 8*(rA0 >> 2) + (rA0 & 3);
  const unsigned short* pK0 = Kp + (s*512 + kA    )*64 + (cb0 >> 1);
  const unsigned short* pK1 = Kp + (s*512 + kA + 4)*64 + (cb1 >> 1);
  const unsigned short* pV0 = Vp + rA0*64 + (cb0 >> 1);
  const unsigned short* pV1 = Vp + rA1*64 + (cb1 >> 1);

  auto STAGE = [&](int buf, int cc){
    char* Kd = smem + SM_KOFF + (s*2 + buf)*4096;
    char* Vd = smem + SM_VOFF + (s*2 + buf)*4096;
    gl16(pK0 + cc*2048, Kd + slot*16);
    gl16(pK1 + cc*2048, Kd + slot*16 + 2048);
    gl16(pV0 + cc*2048, Vd + slot*16);
    gl16(pV1 + cc*2048, Vd + slot*16 + 2048);
  };

  // lane (i,g) scores keys 8g+4f+j; bias idx descends with key
  const int A0 = ((n_ >> 5) - s*16 + 31)*63 + (n_ & 31) + 31 - 8*g;

  auto LDBIAS = [&](int cc, unsigned short* dst){
    const int fb = A0 - 63*cc;
    #pragma unroll
    for (int j = 0; j < 8; j++) dst[j] = tb[fb - j];
  };

  f32x4 O[4] = {};
  float m = -1e30f, l = 0.f, S1 = 0.f, emax = 0.f;   // per-lane partials

  unsigned short ba[8], bb[8];
  STAGE(0, 0);
  LDBIAS(0, ba);

  auto CHUNK = [&](int cc, int buf, unsigned short* bcur, unsigned short* bnxt){
    RAW_BARRIER();                         // prev readers of buf^1 done
    if (cc < 15){
      STAGE(buf ^ 1, cc + 1);
      LDBIAS(cc + 1, bnxt);
      asm volatile("s_waitcnt vmcnt(20)" ::: "memory");   // stage_cc done, prefetch kept
    } else {
      asm volatile("s_waitcnt vmcnt(8)" ::: "memory");
    }
    RAW_BARRIER();                         // all waves' stage_cc visible

    const char* LK = smem + SM_KOFF + (s*2 + buf)*4096;
    const char* LV = smem + SM_VOFF + (s*2 + buf)*4096;

    // ---- QK^T: bias as C-init, Q pre-scaled ----
    __builtin_amdgcn_s_setprio(1);
    float sv[8];
    #pragma unroll
    for (int f = 0; f < 2; f++){
      const int kr = f*16 + i;
      s16x8 ka  = *(const s16x8*)(LK + kr*128 + ((16*g)      ^ ((kr & 7) << 4)));
      s16x8 kb2 = *(const s16x8*)(LK + kr*128 + ((64 + 16*g) ^ ((kr & 7) << 4)));
      f32x4 sf;
      sf[0] = bf2f(bcur[4*f+0]);
      sf[1] = bf2f(bcur[4*f+1]);
      sf[2] = bf2f(bcur[4*f+2]);
      sf[3] = bf2f(bcur[4*f+3]);
      sf = MFMA16(ka,  qf0, sf, 0, 0, 0);
      sf = MFMA16(kb2, qf1, sf, 0, 0, 0);
      sv[4*f+0] = sf[0];
      sv[4*f+1] = sf[1];
      sv[4*f+2] = sf[2];
      sv[4*f+3] = sf[3];
    }
    __builtin_amdgcn_s_setprio(0);

    // ---- max3-shaped tree ----
    float t0 = fmaxf(fmaxf(sv[0], sv[1]), sv[2]);
    float t1 = fmaxf(fmaxf(sv[3], sv[4]), sv[5]);
    float t2 = fmaxf(fmaxf(sv[6], sv[7]), t0);
    float ltmax = fmaxf(t1, t2);

    if (!__all(ltmax - m <= 8.0f)){
      float rmax = fmaxf(ltmax, __shfl_xor(ltmax, 16, 64));
      rmax = fmaxf(rmax, __shfl_xor(rmax, 32, 64));
      float m_new = fmaxf(m, rmax);
      float alpha = exp2f(m - m_new);
      S1 = alpha * (S1 + (m - m_new) * l);
      l *= alpha;
      emax *= alpha;
      #pragma unroll
      for (int r = 0; r < 4; r++){
        float ar = __shfl(alpha, 4*g + r, 64);
        #pragma unroll
        for (int nf = 0; nf < 4; nf++) O[nf][r] *= ar;
      }
      m = m_new;
    }

    float e[8];
    float tl = 0.f, tS1 = 0.f;
    #pragma unroll
    for (int j = 0; j < 8; j++){
      float dd = sv[j] - m;
      float ee = exp2f(dd);
      e[j] = ee; tl += ee; tS1 += ee * dd;
    }
    l  += tl;
    S1 += tS1;
    emax = fmaxf(emax, exp2f(ltmax - m));

    union { s16x8 v; unsigned u[4]; } P;
    P.u[0] = pk2t(e[0], e[1]);
    P.u[1] = pk2t(e[2], e[3]);
    P.u[2] = pk2t(e[4], e[5]);
    P.u[3] = pk2t(e[6], e[7]);
    s16x8 pa = P.v;

    // ---- PV ----
    __builtin_amdgcn_s_setprio(1);
    #pragma unroll
    for (int nf = 0; nf < 4; nf++){
      const int jr = nf*8 + (i >> 1);
      s16x8 vf = *(const s16x8*)(LV + jr*128 + (((i & 1)*64 + 16*g) ^ ((jr & 7) << 4)));
      O[nf] = MFMA16(pa, vf, O[nf], 0, 0, 0);
    }
    __builtin_amdgcn_s_setprio(0);
  };

  for (int c2 = 0; c2 < 16; c2 += 2){
    CHUNK(c2,     0, ba, bb);
    CHUNK(c2 + 1, 1, bb, ba);
  }

  // ---- reduce per-lane partials across g ----
  float l2 = l + __shfl_xor(l, 16, 64);
  float lrow = l2 + __shfl_xor(l2, 32, 64);
  float s2 = S1 + __shfl_xor(S1, 16, 64);
  float S1row = s2 + __shfl_xor(s2, 32, 64);
  float e2 = fmaxf(emax, __shfl_xor(emax, 16, 64));
  float emrow = fmaxf(e2, __shfl_xor(e2, 32, 64));

  __syncthreads();
  float* sO  = (float*)smem;
  float* sML = (float*)(smem + 17408);
  #pragma unroll
  for (int nf = 0; nf < 4; nf++)
    #pragma unroll
    for (int r = 0; r < 4; r++)
      sO[(w*16 + 4*g + r)*68 + nf*16 + i] = O[nf][r];
  if (lane < 16){
    float* p = sML + (w*16 + i)*4;
    p[0] = m; p[1] = lrow; p[2] = S1row; p[3] = emrow;
  }
  __syncthreads();

  if (w < 2){
    const float* p0 = sML + (w*16 + i)*4;
    const float* p1 = sML + ((w+2)*16 + i)*4;
    float m0 = p0[0], l0 = p0[1], s0v = p0[2], e0 = p0[3];
    float m1 = p1[0], l1 = p1[1], s1v = p1[2], e1 = p1[3];
    float M  = fmaxf(m0, m1);
    float a0 = exp2f(m0 - M), a1 = exp2f(m1 - M);
    float L   = a0*l0 + a1*l1;
    float S1c = a0*(s0v + (m0 - M)*l0) + a1*(s1v + (m1 - M)*l1);
    float emc = fmaxf(a0*e0, a1*e1);
    float inv = 1.0f / L;

    union { s16x8 v[2]; unsigned short u[16]; } ob;
    #pragma unroll
    for (int j4 = 0; j4 < 4; j4++){
      float4 x0 = *(const float4*)&sO[(w*16 + i)*68 + g*16 + j4*4];
      float4 x1 = *(const float4*)&sO[((w+2)*16 + i)*68 + g*16 + j4*4];
      ob.u[j4*4+0] = f2bf((a0*x0.x + a1*x1.x) * inv);
      ob.u[j4*4+1] = f2bf((a0*x0.y + a1*x1.y) * inv);
      ob.u[j4*4+2] = f2bf((a0*x0.z + a1*x1.z) * inv);
      ob.u[j4*4+3] = f2bf((a0*x0.w + a1*x1.w) * inv);
    }
    unsigned short* yp = yb + ((size_t)(b << 10) + q0 + w*16 + i) * 512 + h*64 + g*16;
    *(s16x8*)yp       = ob.v[0];
    *(s16x8*)(yp + 8) = ob.v[1];

    float ent = __logf(L) - LN2 * S1c * inv;
    float esum = (g == 0) ? ent : 0.f;
    float wmax = emc * inv;
    #pragma unroll
    for (int off = 1; off < 64; off <<= 1){
      esum += __shfl_xor(esum, off, 64);
      wmax = fmaxf(wmax, __shfl_xor(wmax, off, 64));
    }
    if (lane == 0){ sE[w] = esum; sMx[w] = wmax; }
  }
  __syncthreads();
  if (tid == 0){
    entp[d] = sE[0] + sE[1];
    maxp[d] = fmaxf(sMx[0], sMx[1]);
  }
}

// ------- GEMM2: out = y @ Wproj^T, 64x64 tile, dbuf + raw barriers; block(0,0) finalizes -------
__global__ __launch_bounds__(256) void gemm_proj(
    const unsigned short* __restrict__ A,   // yb [4096][512]
    const unsigned short* __restrict__ Bt,  // wprojb [512][512]
    float* __restrict__ out,
    const float* __restrict__ entp, const float* __restrict__ maxp,
    float* __restrict__ scal)
{
  __shared__ __align__(16) unsigned short lA[2][64*32];
  __shared__ __align__(16) unsigned short lB[2][64*32];
  const int tid = threadIdx.x;
  const int lane = tid & 63;
  const int wid  = tid >> 6;
  const int i = lane & 15, g = lane >> 4;
  const int m0 = blockIdx.x * 64;
  const int n0 = blockIdx.y * 64;
  const int wr = wid >> 1, wc = wid & 1;   // wave tile 32 x 32
  const int K = 512;
  const int srA = tid >> 2;
  const int scc = (tid & 3) * 8;
  const unsigned short* ApS = A  + (size_t)(m0 + srA) * K + scc;
  const unsigned short* BpS = Bt + (size_t)(n0 + srA) * K + scc;

  auto STAGE = [&](int buf, int k0){
    gl16(ApS + k0, &lA[buf][srA*32 + scc]);
    gl16(BpS + k0, &lB[buf][srA*32 + scc]);
  };

  f32x4 acc[2][2] = {};
  STAGE(0, 0);
  for (int k0 = 0; k0 < K; k0 += 32){
    const int buf = (k0 >> 5) & 1;
    RAW_BARRIER();
    if (k0 + 32 < K){
      STAGE(buf ^ 1, k0 + 32);
      asm volatile("s_waitcnt vmcnt(2)" ::: "memory");
    } else {
      asm volatile("s_waitcnt vmcnt(0)" ::: "memory");
    }
    RAW_BARRIER();
    s16x8 aF[2], bF[2];
    #pragma unroll
    for (int mi = 0; mi < 2; mi++)
      aF[mi] = *(const s16x8*)(&lA[buf][(wr*32 + mi*16 + i)*32 + 8*g]);
    #pragma unroll
    for (int ni = 0; ni < 2; ni++)
      bF[ni] = *(const s16x8*)(&lB[buf][(wc*32 + ni*16 + i)*32 + 8*g]);
    #pragma unroll
    for (int mi = 0; mi < 2; mi++)
      #pragma unroll
      for (int ni = 0; ni < 2; ni++)
        acc[mi][ni] = MFMA16(aF[mi], bF[ni], acc[mi][ni], 0, 0, 0);
  }
  #pragma unroll
  for (int mi = 0; mi < 2; mi++){
    #pragma unroll
    for (int r = 0; r < 4; r++){
      int row = m0 + wr*32 + mi*16 + 4*g + r;
      #pragma unroll
      for (int ni = 0; ni < 2; ni++){
        int col = n0 + wc*32 + ni*16 + i;
        out[(size_t)row * 512 + col] = acc[mi][ni][r];
      }
    }
  }

  // ---- fused finalize ----
  if (blockIdx.x == 0 && blockIdx.y == 0 && tid < 64){
    float e = 0.f, mx = -1e30f;
    for (int j = tid; j < 1024; j += 64){
      e += entp[j];
      mx = fmaxf(mx, maxp[j]);
    }
    #pragma unroll
    for (int off = 1; off < 64; off <<= 1){
      e += __shfl_xor(e, off, 64);
      mx = fmaxf(mx, __shfl_xor(mx, off, 64));
    }
    if (tid == 0){
      scal[0] = e / 32768.0f;
      scal[1] = mx;
      scal[2] = 1.0f / 1024.0f;
    }
  }
}

extern "C" void kernel_launch(void* const* d_in, const int* in_sizes, int n_in,
                              void* d_out, int out_size, void* d_ws, size_t ws_size,
                              hipStream_t stream){
  const float* x     = (const float*)d_in[0];
  const float* Wqkv  = (const float*)d_in[1];
  const float* Wproj = (const float*)d_in[2];
  const float* table = (const float*)d_in[3];
  const int*   index = (const int*)d_in[4];   // unused: relpos index is analytic
  (void)index;
  float* out = (float*)d_out;
  char* ws = (char*)d_ws;

  unsigned short* wqkvb  = (unsigned short*)(ws + 4194304);    //  1.5 MB
  unsigned short* wprojb = (unsigned short*)(ws + 5767168);    //  0.5 MB
  unsigned short* qb     = (unsigned short*)(ws + 6291456);    //  4 MB
  unsigned short* kb     = (unsigned short*)(ws + 10485760);   //  4 MB
  unsigned short* vt2    = (unsigned short*)(ws + 14680064);   //  4 MB
  unsigned short* yb     = (unsigned short*)(ws + 18874368);   //  4 MB
  unsigned short* tableb = (unsigned short*)(ws + 23068672);   // 64 KB [8][4096]
  float* entp            = (float*)(ws + 39845888);            //  4 KB (1024)
  float* maxp            = (float*)(ws + 39849984);            //  4 KB (1024)

  cvt_all<<<1040, 256, 0, stream>>>(Wqkv, Wproj, table, wqkvb, wprojb, tableb);
  gemm_qkv<<<dim3(64, 12), 256, 0, stream>>>(x, wqkvb, qb, kb, vt2);
  attn<<<1024, 256, 0, stream>>>(qb, kb, vt2, tableb, yb, entp, maxp);
  gemm_proj<<<dim3(64, 8), 256, 0, stream>>>(yb, wprojb, out, entp, maxp, out + 2097152);
}

// Round 19
// 63.901 us; speedup vs baseline: 1.0154x; 1.0154x over previous
//
#include <hip/hip_runtime.h>

#define SCALE2  0.180336880f     // 0.125 * log2(e)  -> scores in log2 units
#define LOG2E   1.44269504089f
#define LN2     0.69314718056f

typedef __attribute__((ext_vector_type(4))) float f32x4;
typedef __attribute__((ext_vector_type(8))) short s16x8;   // 8 bf16 (4 VGPRs)

#define MFMA16 __builtin_amdgcn_mfma_f32_16x16x32_bf16
#define RAW_BARRIER() asm volatile("s_barrier" ::: "memory")

__device__ __forceinline__ unsigned short f2bf(float f){
  union { float f; unsigned u; } v; v.f = f;
  unsigned r = v.u + 0x7FFFu + ((v.u >> 16) & 1u);   // RNE
  return (unsigned short)(r >> 16);
}
__device__ __forceinline__ float bf2f(unsigned short u){
  union { unsigned u; float f; } v; v.u = ((unsigned)u) << 16; return v.f;
}
// truncating bf16 pack of (a,b) -> one dword via v_perm (1 instr); a in low short
__device__ __forceinline__ unsigned pk2t(float a, float b){
  return __builtin_amdgcn_perm(__float_as_uint(b), __float_as_uint(a), 0x07060302u);
}
__device__ __forceinline__ void gl16(const void* g, void* l){
  __builtin_amdgcn_global_load_lds((const __attribute__((address_space(1))) unsigned int*)g,
                                   (__attribute__((address_space(3))) unsigned int*)l, 16, 0, 0);
}

// ------- fused fp32->bf16: x, Wqkv, Wproj, and relpos table (transposed, log2e-scaled) -------
__global__ void cvt_all(const float* __restrict__ x, const float* __restrict__ wq,
                        const float* __restrict__ wp, const float* __restrict__ table,
                        unsigned short* __restrict__ xb, unsigned short* __restrict__ wqb,
                        unsigned short* __restrict__ wpb, unsigned short* __restrict__ tableb){
  int idx = blockIdx.x * blockDim.x + threadIdx.x;
  if (idx < 786432){
    const float4* s; ushort4* d; int j;
    if (idx < 524288){ s = (const float4*)x;  d = (ushort4*)xb;  j = idx; }
    else if (idx < 720896){ s = (const float4*)wq; d = (ushort4*)wqb; j = idx - 524288; }
    else { s = (const float4*)wp; d = (ushort4*)wpb; j = idx - 720896; }
    float4 v = s[j];
    ushort4 o;
    o.x = f2bf(v.x); o.y = f2bf(v.y); o.z = f2bf(v.z); o.w = f2bf(v.w);
    d[j] = o;
  } else {
    int j = idx - 786432;            // 0..4095 ; table is [3969][8]
    float tv[8] = {0,0,0,0,0,0,0,0};
    if (j < 3969){
      const float4* t4 = (const float4*)table + (size_t)j * 2;
      float4 f0 = t4[0], f1 = t4[1];
      tv[0]=f0.x; tv[1]=f0.y; tv[2]=f0.z; tv[3]=f0.w;
      tv[4]=f1.x; tv[5]=f1.y; tv[6]=f1.z; tv[7]=f1.w;
    }
    #pragma unroll
    for (int h = 0; h < 8; h++)
      tableb[(h << 12) + j] = f2bf(tv[h] * LOG2E);
  }
}

// ---- GEMM1: qkv = x @ Wqkv^T, 64x128 tile, dbuf + raw barriers; Q pre-scaled, V transposed ----
__global__ __launch_bounds__(256) void gemm_qkv(
    const unsigned short* __restrict__ A,    // xb [4096][512]
    const unsigned short* __restrict__ Bt,   // wqkvb [1536][512]
    unsigned short* __restrict__ qb, unsigned short* __restrict__ kb,
    unsigned short* __restrict__ vt2)        // [bh][32cc][32j][2dl][32k]
{
  __shared__ __align__(16) unsigned short lA[2][64*32];
  __shared__ __align__(16) unsigned short lB[2][128*32];
  __shared__ __align__(16) unsigned short lT[64*130];   // V-transpose tile (epilogue only)
  const int tid = threadIdx.x;
  const int lane = tid & 63;
  const int wid  = tid >> 6;
  const int i = lane & 15, g = lane >> 4;
  const int m0 = blockIdx.x * 64;
  const int n0 = blockIdx.y * 128;
  const int wr = wid >> 1, wc = wid & 1;   // wave tile 32 x 64
  const int K = 512;
  const int srA = tid >> 2;                // 0..63
  const int scc = (tid & 3) * 8;
  const unsigned short* ApS  = A  + (size_t)(m0 + srA) * K + scc;
  const unsigned short* BpS0 = Bt + (size_t)(n0 + srA) * K + scc;
  const unsigned short* BpS1 = Bt + (size_t)(n0 + 64 + srA) * K + scc;

  auto STAGE = [&](int buf, int k0){
    gl16(ApS + k0,  &lA[buf][srA*32 + scc]);
    gl16(BpS0 + k0, &lB[buf][srA*32 + scc]);
    gl16(BpS1 + k0, &lB[buf][(64 + srA)*32 + scc]);
  };

  f32x4 acc[2][4] = {};
  STAGE(0, 0);
  for (int k0 = 0; k0 < K; k0 += 32){
    const int buf = (k0 >> 5) & 1;
    RAW_BARRIER();                       // prev readers of buf^1 done
    if (k0 + 32 < K){
      STAGE(buf ^ 1, k0 + 32);
      asm volatile("s_waitcnt vmcnt(3)" ::: "memory");   // this wave's stage_k done
    } else {
      asm volatile("s_waitcnt vmcnt(0)" ::: "memory");
    }
    RAW_BARRIER();                       // all waves' stage_k visible
    s16x8 aF[2], bF[4];
    #pragma unroll
    for (int mi = 0; mi < 2; mi++)
      aF[mi] = *(const s16x8*)(&lA[buf][(wr*32 + mi*16 + i)*32 + 8*g]);
    #pragma unroll
    for (int ni = 0; ni < 4; ni++)
      bF[ni] = *(const s16x8*)(&lB[buf][(wc*64 + ni*16 + i)*32 + 8*g]);
    #pragma unroll
    for (int mi = 0; mi < 2; mi++)
      #pragma unroll
      for (int ni = 0; ni < 4; ni++)
        acc[mi][ni] = MFMA16(aF[mi], bF[ni], acc[mi][ni], 0, 0, 0);
  }

  if (blockIdx.y < 8){
    // ---- q/k epilogue: [bh][tok][dh] scatter; q pre-scaled by SCALE2 ----
    #pragma unroll
    for (int mi = 0; mi < 2; mi++){
      #pragma unroll
      for (int r = 0; r < 4; r++){
        int row = m0 + wr*32 + mi*16 + 4*g + r;
        int b = row >> 10, tok = row & 1023;
        #pragma unroll
        for (int ni = 0; ni < 4; ni++){
          int col = n0 + wc*64 + ni*16 + i;
          int part = col >> 9;
          float av = acc[mi][ni][r];
          unsigned short bv = f2bf(part == 0 ? av * SCALE2 : av);
          int hh = (col >> 6) & 7;
          int dh = col & 63;
          int bh = b * 8 + hh;
          unsigned short* dst = (part == 0) ? qb : kb;
          dst[((size_t)(bh << 10) + tok) * 64 + dh] = bv;
        }
      }
    }
  } else {
    // ---- V epilogue: transpose in LDS, write vt2 coalesced ----
    #pragma unroll
    for (int mi = 0; mi < 2; mi++){
      #pragma unroll
      for (int r = 0; r < 4; r++){
        int lt = wr*32 + mi*16 + 4*g + r;          // local tok
        #pragma unroll
        for (int ni = 0; ni < 4; ni++){
          int lc = wc*64 + ni*16 + i;              // local col 0..127
          lT[lt*130 + lc] = f2bf(acc[mi][ni][r]);
        }
      }
    }
    __syncthreads();
    const int b    = m0 >> 10;
    const int tok0 = m0 & 1023;
    const int lc   = tid >> 1;                     // 0..127
    const int half = tid & 1;                      // which 32-tok chunk
    const int h    = (blockIdx.y - 8)*2 + (lc >> 6);
    const int dh   = lc & 63;
    const int bh   = b*8 + h;
    const int cc   = (tok0 >> 5) + half;
    union { s16x8 v[4]; unsigned short u[32]; } o;
    #pragma unroll
    for (int kk = 0; kk < 32; kk++)
      o.u[kk] = lT[(half*32 + kk)*130 + lc];
    unsigned short* dst = vt2 + (size_t)bh*65536 + ((size_t)cc*32 + (dh >> 1))*64 + (dh & 1)*32;
    *(s16x8*)(dst +  0) = o.v[0];
    *(s16x8*)(dst +  8) = o.v[1];
    *(s16x8*)(dst + 16) = o.v[2];
    *(s16x8*)(dst + 24) = o.v[3];
  }
}

// ---- Flash attention v13: bias as MFMA C-init + pre-scaled Q ----
#define SM_KOFF 0
#define SM_VOFF 16384
#define SM_SIZE 32768
__global__ __launch_bounds__(256, 4) void attn(
    const unsigned short* __restrict__ qb,     // pre-scaled by SCALE2
    const unsigned short* __restrict__ kb,
    const unsigned short* __restrict__ vt2,    // [bh][32cc][32j][2dl][32k]
    const unsigned short* __restrict__ tableb, // [8][4096] bf16, log2e-scaled
    unsigned short* __restrict__ yb,
    float* __restrict__ entp, float* __restrict__ maxp)
{
  __shared__ __align__(16) char smem[SM_SIZE];
  __shared__ float sE[2], sMx[2];

  const int tid = threadIdx.x, lane = tid & 63, w = tid >> 6;
  const int i = lane & 15, g = lane >> 4;

  // XCD-affine decode: all 32 blocks of one (b,h) share d&7 -> same XCD L2
  const int d  = blockIdx.x;
  const int bh = (d & 7) * 4 + (d >> 8);
  const int qt = (d >> 3) & 31;
  const int q0 = qt * 32;
  const int b  = bh >> 3;
  const int h  = bh & 7;

  const int qs = w & 1;        // q sub-tile
  const int s  = w >> 1;       // kv half

  const unsigned short* Qp = qb  + (size_t)bh * 65536;
  const unsigned short* Kp = kb  + (size_t)bh * 65536;
  const unsigned short* Vp = vt2 + (size_t)bh * 65536 + (size_t)s * 32768;
  const unsigned short* tb = tableb + (h << 12);

  const int n_ = q0 + qs*16 + i;
  s16x8 qf0 = *(const s16x8*)(Qp + (size_t)n_ * 64 + 8*g);
  s16x8 qf1 = *(const s16x8*)(Qp + (size_t)n_ * 64 + 32 + 8*g);

  const int slot = qs*64 + lane;
  const int rA0 = slot >> 3, rA1 = rA0 + 16;            // LDS dest rows
  const int cb0 = ((slot & 7)*16) ^ ((rA0 & 7) << 4);
  const int cb1 = ((slot & 7)*16) ^ ((rA1 & 7) << 4);
  // K storage permutation: LDS row x holds key 8*(x>>2)+(x&3) (+4 for x>=16)
  const int kA = 8*(rA0 >> 2) + (rA0 & 3);
  const unsigned short* pK0 = Kp + (s*512 + kA    )*64 + (cb0 >> 1);
  const unsigned short* pK1 = Kp + (s*512 + kA + 4)*64 + (cb1 >> 1);
  const unsigned short* pV0 = Vp + rA0*64 + (cb0 >> 1);
  const unsigned short* pV1 = Vp + rA1*64 + (cb1 >> 1);

  auto STAGE = [&](int buf, int cc){
    char* Kd = smem + SM_KOFF + (s*2 + buf)*4096;
    char* Vd = smem + SM_VOFF + (s*2 + buf)*4096;
    gl16(pK0 + cc*2048, Kd + slot*16);
    gl16(pK1 + cc*2048, Kd + slot*16 + 2048);
    gl16(pV0 + cc*2048, Vd + slot*16);
    gl16(pV1 + cc*2048, Vd + slot*16 + 2048);
  };

  // lane (i,g) scores keys 8g+4f+j; bias idx descends with key
  const int A0 = ((n_ >> 5) - s*16 + 31)*63 + (n_ & 31) + 31 - 8*g;

  auto LDBIAS = [&](int cc, unsigned short* dst){
    const int fb = A0 - 63*cc;
    #pragma unroll
    for (int j = 0; j < 8; j++) dst[j] = tb[fb - j];
  };

  f32x4 O[4] = {};
  float m = -1e30f, l = 0.f, S1 = 0.f, emax = 0.f;   // per-lane partials

  unsigned short ba[8], bb[8];
  STAGE(0, 0);
  LDBIAS(0, ba);

  auto CHUNK = [&](int cc, int buf, unsigned short* bcur, unsigned short* bnxt){
    RAW_BARRIER();                         // prev readers of buf^1 done
    if (cc < 15){
      STAGE(buf ^ 1, cc + 1);
      LDBIAS(cc + 1, bnxt);
      asm volatile("s_waitcnt vmcnt(20)" ::: "memory");   // stage_cc done, prefetch kept
    } else {
      asm volatile("s_waitcnt vmcnt(8)" ::: "memory");
    }
    RAW_BARRIER();                         // all waves' stage_cc visible

    const char* LK = smem + SM_KOFF + (s*2 + buf)*4096;
    const char* LV = smem + SM_VOFF + (s*2 + buf)*4096;

    // ---- QK^T: bias as C-init, Q pre-scaled ----
    __builtin_amdgcn_s_setprio(1);
    float sv[8];
    #pragma unroll
    for (int f = 0; f < 2; f++){
      const int kr = f*16 + i;
      s16x8 ka  = *(const s16x8*)(LK + kr*128 + ((16*g)      ^ ((kr & 7) << 4)));
      s16x8 kb2 = *(const s16x8*)(LK + kr*128 + ((64 + 16*g) ^ ((kr & 7) << 4)));
      f32x4 sf;
      sf[0] = bf2f(bcur[4*f+0]);
      sf[1] = bf2f(bcur[4*f+1]);
      sf[2] = bf2f(bcur[4*f+2]);
      sf[3] = bf2f(bcur[4*f+3]);
      sf = MFMA16(ka,  qf0, sf, 0, 0, 0);
      sf = MFMA16(kb2, qf1, sf, 0, 0, 0);
      sv[4*f+0] = sf[0];
      sv[4*f+1] = sf[1];
      sv[4*f+2] = sf[2];
      sv[4*f+3] = sf[3];
    }
    __builtin_amdgcn_s_setprio(0);

    // ---- max3-shaped tree ----
    float t0 = fmaxf(fmaxf(sv[0], sv[1]), sv[2]);
    float t1 = fmaxf(fmaxf(sv[3], sv[4]), sv[5]);
    float t2 = fmaxf(fmaxf(sv[6], sv[7]), t0);
    float ltmax = fmaxf(t1, t2);

    if (!__all(ltmax - m <= 8.0f)){
      float rmax = fmaxf(ltmax, __shfl_xor(ltmax, 16, 64));
      rmax = fmaxf(rmax, __shfl_xor(rmax, 32, 64));
      float m_new = fmaxf(m, rmax);
      float alpha = exp2f(m - m_new);
      S1 = alpha * (S1 + (m - m_new) * l);
      l *= alpha;
      emax *= alpha;
      #pragma unroll
      for (int r = 0; r < 4; r++){
        float ar = __shfl(alpha, 4*g + r, 64);
        #pragma unroll
        for (int nf = 0; nf < 4; nf++) O[nf][r] *= ar;
      }
      m = m_new;
    }

    float e[8];
    float tl = 0.f, tS1 = 0.f;
    #pragma unroll
    for (int j = 0; j < 8; j++){
      float dd = sv[j] - m;
      float ee = exp2f(dd);
      e[j] = ee; tl += ee; tS1 += ee * dd;
    }
    l  += tl;
    S1 += tS1;
    emax = fmaxf(emax, exp2f(ltmax - m));

    union { s16x8 v; unsigned u[4]; } P;
    P.u[0] = pk2t(e[0], e[1]);
    P.u[1] = pk2t(e[2], e[3]);
    P.u[2] = pk2t(e[4], e[5]);
    P.u[3] = pk2t(e[6], e[7]);
    s16x8 pa = P.v;

    // ---- PV ----
    __builtin_amdgcn_s_setprio(1);
    #pragma unroll
    for (int nf = 0; nf < 4; nf++){
      const int jr = nf*8 + (i >> 1);
      s16x8 vf = *(const s16x8*)(LV + jr*128 + (((i & 1)*64 + 16*g) ^ ((jr & 7) << 4)));
      O[nf] = MFMA16(pa, vf, O[nf], 0, 0, 0);
    }
    __builtin_amdgcn_s_setprio(0);
  };

  for (int c2 = 0; c2 < 16; c2 += 2){
    CHUNK(c2,     0, ba, bb);
    CHUNK(c2 + 1, 1, bb, ba);
  }

  // ---- reduce per-lane partials across g ----
  float l2 = l + __shfl_xor(l, 16, 64);
  float lrow = l2 + __shfl_xor(l2, 32, 64);
  float s2 = S1 + __shfl_xor(S1, 16, 64);
  float S1row = s2 + __shfl_xor(s2, 32, 64);
  float e2 = fmaxf(emax, __shfl_xor(emax, 16, 64));
  float emrow = fmaxf(e2, __shfl_xor(e2, 32, 64));

  __syncthreads();
  float* sO  = (float*)smem;
  float* sML = (float*)(smem + 17408);
  #pragma unroll
  for (int nf = 0; nf < 4; nf++)
    #pragma unroll
    for (int r = 0; r < 4; r++)
      sO[(w*16 + 4*g + r)*68 + nf*16 + i] = O[nf][r];
  if (lane < 16){
    float* p = sML + (w*16 + i)*4;
    p[0] = m; p[1] = lrow; p[2] = S1row; p[3] = emrow;
  }
  __syncthreads();

  if (w < 2){
    const float* p0 = sML + (w*16 + i)*4;
    const float* p1 = sML + ((w+2)*16 + i)*4;
    float m0 = p0[0], l0 = p0[1], s0v = p0[2], e0 = p0[3];
    float m1 = p1[0], l1 = p1[1], s1v = p1[2], e1 = p1[3];
    float M  = fmaxf(m0, m1);
    float a0 = exp2f(m0 - M), a1 = exp2f(m1 - M);
    float L   = a0*l0 + a1*l1;
    float S1c = a0*(s0v + (m0 - M)*l0) + a1*(s1v + (m1 - M)*l1);
    float emc = fmaxf(a0*e0, a1*e1);
    float inv = 1.0f / L;

    union { s16x8 v[2]; unsigned short u[16]; } ob;
    #pragma unroll
    for (int j4 = 0; j4 < 4; j4++){
      float4 x0 = *(const float4*)&sO[(w*16 + i)*68 + g*16 + j4*4];
      float4 x1 = *(const float4*)&sO[((w+2)*16 + i)*68 + g*16 + j4*4];
      ob.u[j4*4+0] = f2bf((a0*x0.x + a1*x1.x) * inv);
      ob.u[j4*4+1] = f2bf((a0*x0.y + a1*x1.y) * inv);
      ob.u[j4*4+2] = f2bf((a0*x0.z + a1*x1.z) * inv);
      ob.u[j4*4+3] = f2bf((a0*x0.w + a1*x1.w) * inv);
    }
    unsigned short* yp = yb + ((size_t)(b << 10) + q0 + w*16 + i) * 512 + h*64 + g*16;
    *(s16x8*)yp       = ob.v[0];
    *(s16x8*)(yp + 8) = ob.v[1];

    float ent = __logf(L) - LN2 * S1c * inv;
    float esum = (g == 0) ? ent : 0.f;
    float wmax = emc * inv;
    #pragma unroll
    for (int off = 1; off < 64; off <<= 1){
      esum += __shfl_xor(esum, off, 64);
      wmax = fmaxf(wmax, __shfl_xor(wmax, off, 64));
    }
    if (lane == 0){ sE[w] = esum; sMx[w] = wmax; }
  }
  __syncthreads();
  if (tid == 0){
    entp[d] = sE[0] + sE[1];
    maxp[d] = fmaxf(sMx[0], sMx[1]);
  }
}

// ------- GEMM2: out = y @ Wproj^T, 64x64 tile, dbuf + raw barriers; block(0,0) finalizes -------
__global__ __launch_bounds__(256) void gemm_proj(
    const unsigned short* __restrict__ A,   // yb [4096][512]
    const unsigned short* __restrict__ Bt,  // wprojb [512][512]
    float* __restrict__ out,
    const float* __restrict__ entp, const float* __restrict__ maxp,
    float* __restrict__ scal)
{
  __shared__ __align__(16) unsigned short lA[2][64*32];
  __shared__ __align__(16) unsigned short lB[2][64*32];
  const int tid = threadIdx.x;
  const int lane = tid & 63;
  const int wid  = tid >> 6;
  const int i = lane & 15, g = lane >> 4;
  const int m0 = blockIdx.x * 64;
  const int n0 = blockIdx.y * 64;
  const int wr = wid >> 1, wc = wid & 1;   // wave tile 32 x 32
  const int K = 512;
  const int srA = tid >> 2;
  const int scc = (tid & 3) * 8;
  const unsigned short* ApS = A  + (size_t)(m0 + srA) * K + scc;
  const unsigned short* BpS = Bt + (size_t)(n0 + srA) * K + scc;

  auto STAGE = [&](int buf, int k0){
    gl16(ApS + k0, &lA[buf][srA*32 + scc]);
    gl16(BpS + k0, &lB[buf][srA*32 + scc]);
  };

  f32x4 acc[2][2] = {};
  STAGE(0, 0);
  for (int k0 = 0; k0 < K; k0 += 32){
    const int buf = (k0 >> 5) & 1;
    RAW_BARRIER();
    if (k0 + 32 < K){
      STAGE(buf ^ 1, k0 + 32);
      asm volatile("s_waitcnt vmcnt(2)" ::: "memory");
    } else {
      asm volatile("s_waitcnt vmcnt(0)" ::: "memory");
    }
    RAW_BARRIER();
    s16x8 aF[2], bF[2];
    #pragma unroll
    for (int mi = 0; mi < 2; mi++)
      aF[mi] = *(const s16x8*)(&lA[buf][(wr*32 + mi*16 + i)*32 + 8*g]);
    #pragma unroll
    for (int ni = 0; ni < 2; ni++)
      bF[ni] = *(const s16x8*)(&lB[buf][(wc*32 + ni*16 + i)*32 + 8*g]);
    #pragma unroll
    for (int mi = 0; mi < 2; mi++)
      #pragma unroll
      for (int ni = 0; ni < 2; ni++)
        acc[mi][ni] = MFMA16(aF[mi], bF[ni], acc[mi][ni], 0, 0, 0);
  }
  #pragma unroll
  for (int mi = 0; mi < 2; mi++){
    #pragma unroll
    for (int r = 0; r < 4; r++){
      int row = m0 + wr*32 + mi*16 + 4*g + r;
      #pragma unroll
      for (int ni = 0; ni < 2; ni++){
        int col = n0 + wc*32 + ni*16 + i;
        out[(size_t)row * 512 + col] = acc[mi][ni][r];
      }
    }
  }

  // ---- fused finalize ----
  if (blockIdx.x == 0 && blockIdx.y == 0 && tid < 64){
    float e = 0.f, mx = -1e30f;
    for (int j = tid; j < 1024; j += 64){
      e += entp[j];
      mx = fmaxf(mx, maxp[j]);
    }
    #pragma unroll
    for (int off = 1; off < 64; off <<= 1){
      e += __shfl_xor(e, off, 64);
      mx = fmaxf(mx, __shfl_xor(mx, off, 64));
    }
    if (tid == 0){
      scal[0] = e / 32768.0f;
      scal[1] = mx;
      scal[2] = 1.0f / 1024.0f;
    }
  }
}

extern "C" void kernel_launch(void* const* d_in, const int* in_sizes, int n_in,
                              void* d_out, int out_size, void* d_ws, size_t ws_size,
                              hipStream_t stream){
  const float* x     = (const float*)d_in[0];
  const float* Wqkv  = (const float*)d_in[1];
  const float* Wproj = (const float*)d_in[2];
  const float* table = (const float*)d_in[3];
  const int*   index = (const int*)d_in[4];   // unused: relpos index is analytic
  (void)index;
  float* out = (float*)d_out;
  char* ws = (char*)d_ws;

  unsigned short* xb     = (unsigned short*)(ws + 0);          //  4 MB
  unsigned short* wqkvb  = (unsigned short*)(ws + 4194304);    //  1.5 MB
  unsigned short* wprojb = (unsigned short*)(ws + 5767168);    //  0.5 MB
  unsigned short* qb     = (unsigned short*)(ws + 6291456);    //  4 MB
  unsigned short* kb     = (unsigned short*)(ws + 10485760);   //  4 MB
  unsigned short* vt2    = (unsigned short*)(ws + 14680064);   //  4 MB
  unsigned short* yb     = (unsigned short*)(ws + 18874368);   //  4 MB
  unsigned short* tableb = (unsigned short*)(ws + 23068672);   // 64 KB [8][4096]
  float* entp            = (float*)(ws + 39845888);            //  4 KB (1024)
  float* maxp            = (float*)(ws + 39849984);            //  4 KB (1024)

  cvt_all<<<3088, 256, 0, stream>>>(x, Wqkv, Wproj, table, xb, wqkvb, wprojb, tableb);
  gemm_qkv<<<dim3(64, 12), 256, 0, stream>>>(xb, wqkvb, qb, kb, vt2);
  attn<<<1024, 256, 0, stream>>>(qb, kb, vt2, tableb, yb, entp, maxp);
  gemm_proj<<<dim3(64, 8), 256, 0, stream>>>(yb, wprojb, out, entp, maxp, out + 2097152);
}